// Round 5
// baseline (712.821 us; speedup 1.0000x reference)
//
#include <hip/hip_runtime.h>

#define S 3072
#define D 512
#define H 8

constexpr float LN_EPS = 1e-6f;

typedef __attribute__((ext_vector_type(8))) short bf16x8;   // 8 bf16 = 4 VGPRs
typedef __attribute__((ext_vector_type(4))) float f32x4;    // MFMA C/D frag

__device__ __forceinline__ short f2bf(float f) {            // RNE fp32->bf16
    unsigned int u = __builtin_bit_cast(unsigned int, f);
    u += 0x7FFFu + ((u >> 16) & 1u);
    return (short)(u >> 16);
}

// -------------------- K1: QKV projection --------------------
// x[S,D] @ {Wq,Wk,Wv}[D,512] + b -> bf16 Q,K in [H][S][64] (Q pre-scaled by
// 1/8) and bf16 V^T in [H][64][S]. grid (S/8, 6), block 256.
__global__ void qkv_kernel(const float* __restrict__ x,
                           const float* __restrict__ Wq, const float* __restrict__ bq,
                           const float* __restrict__ Wk, const float* __restrict__ bk,
                           const float* __restrict__ Wv, const float* __restrict__ bv,
                           short* __restrict__ Qb, short* __restrict__ Kb,
                           short* __restrict__ Vt) {
    const int rb = blockIdx.x;
    const int cb = blockIdx.y;
    const int t  = threadIdx.x;
    const int r0 = rb * 8;
    const int gc = cb * 256 + t;     // 0..1535
    const int m  = gc >> 9;          // 0:Q 1:K 2:V
    const int cc = gc & 511;
    const float* W    = (m == 0) ? Wq : (m == 1) ? Wk : Wv;
    const float* bias = (m == 0) ? bq : (m == 1) ? bk : bv;
    const float4* xf4 = (const float4*)(x + (size_t)r0 * D);

    float acc[8];
#pragma unroll
    for (int r = 0; r < 8; ++r) acc[r] = 0.f;

    for (int k4 = 0; k4 < D / 4; ++k4) {
        float w0 = W[(k4 * 4 + 0) * 512 + cc];
        float w1 = W[(k4 * 4 + 1) * 512 + cc];
        float w2 = W[(k4 * 4 + 2) * 512 + cc];
        float w3 = W[(k4 * 4 + 3) * 512 + cc];
#pragma unroll
        for (int r = 0; r < 8; ++r) {
            float4 xv = xf4[r * (D / 4) + k4];   // uniform -> s_load broadcast
            acc[r] += xv.x * w0 + xv.y * w1 + xv.z * w2 + xv.w * w3;
        }
    }
    const float b = bias[cc];
    const int h = cc >> 6, d = cc & 63;
    const float scale = (m == 0) ? 0.125f : 1.0f;
#pragma unroll
    for (int r = 0; r < 8; ++r) {
        float val = (acc[r] + b) * scale;
        if (m == 0)      Qb[(((size_t)h * S + (r0 + r)) << 6) + d] = f2bf(val);
        else if (m == 1) Kb[(((size_t)h * S + (r0 + r)) << 6) + d] = f2bf(val);
        else             Vt[((size_t)h * 64 + d) * S + (r0 + r)]   = f2bf(val);
    }
}

// -------------------- K2: fused logits + entmax-1.5 + PV --------------------
// One wave (64 threads) per 16 q-rows x full S. Recompute-style: logits are
// regenerated by MFMA for each entmax pass (K streams from L2, 393 KB/head).
// D-frag layout (validated r2-r4): col = lane&15 (k), row = (lane>>4)*4 + reg (q).
// Per-row stats reduce across the 16 k-lanes via shfl_xor 1/2/4/8.
// Final pass: write fp32 attn once, LDS-transpose P to A-frag, MFMA with V^T.
__global__ __launch_bounds__(64) void fused_attn_kernel(
        const short* __restrict__ Qb, const short* __restrict__ Kb,
        const short* __restrict__ Vt, float* __restrict__ attn,
        float* __restrict__ AO) {
    __shared__ short plds[16][40];          // P[q][k] 16x32, row stride 40 (80B, ~2-way)
    const int qb = blockIdx.x, h = blockIdx.y;
    const int l = threadIdx.x;              // 0..63, one wave
    const int lr = l & 15, lk = l >> 4;
    const int q0 = qb * 16;                 // wave's q rows
    const short* Qh = Qb + ((size_t)h * S) * 64;
    const short* Kh = Kb + ((size_t)h * S) * 64;
    const short* Vh = Vt + (size_t)h * 64 * S;

    const bf16x8 aq0 = *(const bf16x8*)(Qh + (size_t)(q0 + lr) * 64 + lk * 8);
    const bf16x8 aq1 = *(const bf16x8*)(Qh + (size_t)(q0 + lr) * 64 + 32 + lk * 8);

    const float n = (float)S;

    // ---- Pass A: per-row max / sum / sumsq of logits ----
    float m4[4] = {-1e30f, -1e30f, -1e30f, -1e30f};
    float s4[4] = {}, q4[4] = {};
    for (int kb = 0; kb < S / 16; ++kb) {
        bf16x8 b0 = *(const bf16x8*)(Kh + (size_t)(kb * 16 + lr) * 64 + lk * 8);
        bf16x8 b1 = *(const bf16x8*)(Kh + (size_t)(kb * 16 + lr) * 64 + 32 + lk * 8);
        f32x4 d = (f32x4){0.f, 0.f, 0.f, 0.f};
        d = __builtin_amdgcn_mfma_f32_16x16x32_bf16(aq0, b0, d, 0, 0, 0);
        d = __builtin_amdgcn_mfma_f32_16x16x32_bf16(aq1, b1, d, 0, 0, 0);
#pragma unroll
        for (int r = 0; r < 4; ++r) {
            m4[r] = fmaxf(m4[r], d[r]);
            s4[r] += d[r];
            q4[r] = fmaf(d[r], d[r], q4[r]);
        }
    }
#pragma unroll
    for (int off = 1; off < 16; off <<= 1) {
#pragma unroll
        for (int r = 0; r < 4; ++r) {
            m4[r] = fmaxf(m4[r], __shfl_xor(m4[r], off, 64));
            s4[r] += __shfl_xor(s4[r], off, 64);
            q4[r] += __shfl_xor(q4[r], off, 64);
        }
    }

    // ---- closed-form full-support init (w-space: w=(x-m)/2), thr = m/2 + c ----
    float T4[4];
#pragma unroll
    for (int r = 0; r < 4; ++r) {
        float mean = (s4[r] / n - m4[r]) * 0.5f;
        float msq  = (q4[r] - 2.f * m4[r] * s4[r] + n * m4[r] * m4[r]) * (0.25f / n);
        float ss   = n * (msq - mean * mean);
        float delta = fmaxf((1.f - ss) / n, 0.f);
        float c = mean - sqrtf(delta);
        c = fminf(fmaxf(c, -1.0f), -0.01f);
        T4[r] = 0.5f * m4[r] + c;           // z = 0.5*x - T
    }

    // ---- Pass B: support-exact quadratic iterations (Michelot-style) ----
    for (int it = 0; it < 8; ++it) {
        float f4[4] = {}, fp4[4] = {}, cn4[4] = {};
        for (int kb = 0; kb < S / 16; ++kb) {
            bf16x8 b0 = *(const bf16x8*)(Kh + (size_t)(kb * 16 + lr) * 64 + lk * 8);
            bf16x8 b1 = *(const bf16x8*)(Kh + (size_t)(kb * 16 + lr) * 64 + 32 + lk * 8);
            f32x4 d = (f32x4){0.f, 0.f, 0.f, 0.f};
            d = __builtin_amdgcn_mfma_f32_16x16x32_bf16(aq0, b0, d, 0, 0, 0);
            d = __builtin_amdgcn_mfma_f32_16x16x32_bf16(aq1, b1, d, 0, 0, 0);
#pragma unroll
            for (int r = 0; r < 4; ++r) {
                float z  = fmaf(d[r], 0.5f, -T4[r]);
                float zc = fmaxf(z, 0.f);
                f4[r]  = fmaf(zc, zc, f4[r]);
                fp4[r] += zc;
                cn4[r] += (z > 0.f) ? 1.f : 0.f;
            }
        }
#pragma unroll
        for (int off = 1; off < 16; off <<= 1) {
#pragma unroll
            for (int r = 0; r < 4; ++r) {
                f4[r]  += __shfl_xor(f4[r],  off, 64);
                fp4[r] += __shfl_xor(fp4[r], off, 64);
                cn4[r] += __shfl_xor(cn4[r], off, 64);
            }
        }
        bool conv = true;
#pragma unroll
        for (int r = 0; r < 4; ++r) {
            float ns   = fmaxf(cn4[r], 1.0f);
            float disc = fmaxf(fp4[r] * fp4[r] - ns * (f4[r] - 1.0f), 0.f);
            float del  = (fp4[r] - sqrtf(disc)) / ns;
            T4[r] += del;
            conv = conv && (fabsf(del) < 2e-6f);
        }
        if (__all(conv)) break;
    }

    // ---- Final pass: P write (fp32 attn) + PV accumulation ----
    f32x4 acc[4];
#pragma unroll
    for (int j = 0; j < 4; ++j) acc[j] = (f32x4){0.f, 0.f, 0.f, 0.f};

    float* arow = attn + ((size_t)h * S + q0) * S;
    for (int kb2 = 0; kb2 < S / 32; ++kb2) {
        const int k0 = kb2 * 32;
        bf16x8 b00 = *(const bf16x8*)(Kh + (size_t)(k0 + lr) * 64 + lk * 8);
        bf16x8 b01 = *(const bf16x8*)(Kh + (size_t)(k0 + lr) * 64 + 32 + lk * 8);
        bf16x8 b10 = *(const bf16x8*)(Kh + (size_t)(k0 + 16 + lr) * 64 + lk * 8);
        bf16x8 b11 = *(const bf16x8*)(Kh + (size_t)(k0 + 16 + lr) * 64 + 32 + lk * 8);
        f32x4 d0 = (f32x4){0.f, 0.f, 0.f, 0.f}, d1 = d0;
        d0 = __builtin_amdgcn_mfma_f32_16x16x32_bf16(aq0, b00, d0, 0, 0, 0);
        d0 = __builtin_amdgcn_mfma_f32_16x16x32_bf16(aq1, b01, d0, 0, 0, 0);
        d1 = __builtin_amdgcn_mfma_f32_16x16x32_bf16(aq0, b10, d1, 0, 0, 0);
        d1 = __builtin_amdgcn_mfma_f32_16x16x32_bf16(aq1, b11, d1, 0, 0, 0);
#pragma unroll
        for (int r = 0; r < 4; ++r) {
            float z0 = fmaxf(fmaf(d0[r], 0.5f, -T4[r]), 0.f);
            float z1 = fmaxf(fmaf(d1[r], 0.5f, -T4[r]), 0.f);
            float p0 = z0 * z0, p1 = z1 * z1;
            const int row = lk * 4 + r;
            arow[(size_t)row * S + k0 + lr]      = p0;   // fp32 attn (tuple out #2)
            arow[(size_t)row * S + k0 + 16 + lr] = p1;
            plds[row][lr]      = f2bf(p0);               // P[q][k] for A-frag
            plds[row][16 + lr] = f2bf(p1);
        }
        // same-wave LDS: compiler inserts lgkmcnt; no barrier needed
        bf16x8 a = *(const bf16x8*)&plds[lr][lk * 8];
#pragma unroll
        for (int j = 0; j < 4; ++j) {
            bf16x8 b = *(const bf16x8*)(Vh + (size_t)(j * 16 + lr) * S + k0 + lk * 8);
            acc[j] = __builtin_amdgcn_mfma_f32_16x16x32_bf16(a, b, acc[j], 0, 0, 0);
        }
    }
    float* AOr = AO + ((size_t)h * S + q0) * 64;
#pragma unroll
    for (int j = 0; j < 4; ++j)
#pragma unroll
        for (int r = 0; r < 4; ++r)
            AOr[(size_t)(lk * 4 + r) * 64 + j * 16 + lr] = acc[j][r];
}

// -------------------- K5: out-proj + residual + LayerNorm --------------------
__global__ void outproj_ln_kernel(const float* __restrict__ AO, const float* __restrict__ Wo,
                                  const float* __restrict__ bo, const float* __restrict__ x,
                                  const float* __restrict__ gamma, const float* __restrict__ beta,
                                  float* __restrict__ out) {
    __shared__ float red[8];
    const int rb = blockIdx.x;
    const int t  = threadIdx.x;
    const int s0 = rb * 8;
    float acc0[8] = {}, acc1[8] = {};
    const int c0 = t, c1 = t + 256;
    const float4* A0 = (const float4*)AO;
    for (int k4 = 0; k4 < 128; ++k4) {
        int k = k4 * 4;
        int h = k >> 6, d4 = (k & 63) >> 2;
        float w00 = Wo[(k + 0) * 512 + c0], w10 = Wo[(k + 0) * 512 + c1];
        float w01 = Wo[(k + 1) * 512 + c0], w11 = Wo[(k + 1) * 512 + c1];
        float w02 = Wo[(k + 2) * 512 + c0], w12 = Wo[(k + 2) * 512 + c1];
        float w03 = Wo[(k + 3) * 512 + c0], w13 = Wo[(k + 3) * 512 + c1];
#pragma unroll
        for (int r = 0; r < 8; ++r) {
            float4 a = A0[((size_t)h * S + s0 + r) * 16 + d4];   // uniform
            acc0[r] += a.x * w00 + a.y * w01 + a.z * w02 + a.w * w03;
            acc1[r] += a.x * w10 + a.y * w11 + a.z * w12 + a.w * w13;
        }
    }
    const float b0 = bo[c0], b1 = bo[c1];
    const float g0 = gamma[c0], g1 = gamma[c1];
    const float be0 = beta[c0], be1 = beta[c1];
    const int wave = t >> 6, lane = t & 63;
    for (int r = 0; r < 8; ++r) {
        float y0 = acc0[r] + b0 + x[(size_t)(s0 + r) * 512 + c0];
        float y1 = acc1[r] + b1 + x[(size_t)(s0 + r) * 512 + c1];
        float s = y0 + y1, qq = y0 * y0 + y1 * y1;
#pragma unroll
        for (int off = 32; off; off >>= 1) {
            s  += __shfl_down(s, off, 64);
            qq += __shfl_down(qq, off, 64);
        }
        __syncthreads();
        if (lane == 0) { red[wave * 2] = s; red[wave * 2 + 1] = qq; }
        __syncthreads();
        s  = red[0] + red[2] + red[4] + red[6];
        qq = red[1] + red[3] + red[5] + red[7];
        float mu  = s * (1.0f / 512.0f);
        float var = qq * (1.0f / 512.0f) - mu * mu;
        float inv = rsqrtf(var + LN_EPS);
        out[(size_t)(s0 + r) * 512 + c0] = (y0 - mu) * inv * g0 + be0;
        out[(size_t)(s0 + r) * 512 + c1] = (y1 - mu) * inv * g1 + be1;
    }
}

extern "C" void kernel_launch(void* const* d_in, const int* in_sizes, int n_in,
                              void* d_out, int out_size, void* d_ws, size_t ws_size,
                              hipStream_t stream) {
    const float* x     = (const float*)d_in[0];
    const float* Wq    = (const float*)d_in[1];
    const float* bq    = (const float*)d_in[2];
    const float* Wk    = (const float*)d_in[3];
    const float* bk    = (const float*)d_in[4];
    const float* Wv    = (const float*)d_in[5];
    const float* bv    = (const float*)d_in[6];
    const float* Wo    = (const float*)d_in[7];
    const float* bo    = (const float*)d_in[8];
    const float* gamma = (const float*)d_in[9];
    const float* beta  = (const float*)d_in[10];

    float* out  = (float*)d_out;
    float* attn = out + (size_t)S * D;          // tuple output #2

    short* Qb = (short*)d_ws;                   // [H][S][64] bf16, pre-scaled
    short* Kb = Qb + (size_t)H * S * 64;        // [H][S][64] bf16
    short* Vt = Kb + (size_t)H * S * 64;        // [H][64][S] bf16 (transposed)
    float* AO = (float*)(Vt + (size_t)H * 64 * S);   // [H][S][64] f32

    qkv_kernel<<<dim3(S / 8, 6), 256, 0, stream>>>(x, Wq, bq, Wk, bk, Wv, bv, Qb, Kb, Vt);
    fused_attn_kernel<<<dim3(S / 16, H), 64, 0, stream>>>(Qb, Kb, Vt, attn, AO);
    outproj_ln_kernel<<<dim3(S / 8), 256, 0, stream>>>(AO, Wo, bo, x, gamma, beta, out);
}

// Round 6
// 535.972 us; speedup vs baseline: 1.3300x; 1.3300x over previous
//
#include <hip/hip_runtime.h>

#define S 3072
#define D 512
#define H 8

constexpr float LN_EPS = 1e-6f;

typedef __attribute__((ext_vector_type(8))) short bf16x8;   // 8 bf16 = 4 VGPRs
typedef __attribute__((ext_vector_type(4))) float f32x4;    // MFMA C/D frag

__device__ __forceinline__ short f2bf(float f) {            // RNE fp32->bf16
    unsigned int u = __builtin_bit_cast(unsigned int, f);
    u += 0x7FFFu + ((u >> 16) & 1u);
    return (short)(u >> 16);
}
__device__ __forceinline__ unsigned pack_rne(float lo, float hi) {   // 2xbf16 in u32
    unsigned ul = __builtin_bit_cast(unsigned, lo);
    ul += 0x7FFFu + ((ul >> 16) & 1u);
    unsigned uh = __builtin_bit_cast(unsigned, hi);
    uh += 0x7FFFu + ((uh >> 16) & 1u);
    return (ul >> 16) | (uh & 0xFFFF0000u);
}
__device__ __forceinline__ float unpk_lo(unsigned p) {
    return __builtin_bit_cast(float, p << 16);
}
__device__ __forceinline__ float unpk_hi(unsigned p) {
    return __builtin_bit_cast(float, p & 0xFFFF0000u);
}

// -------------------- K1: QKV projection --------------------
// x[S,D] @ {Wq,Wk,Wv}[D,512] + b -> bf16 Q,K in [H][S][64] (Q pre-scaled by
// 1/8) and bf16 V^T in [H][64][S]. grid (S/8, 6), block 256.
__global__ void qkv_kernel(const float* __restrict__ x,
                           const float* __restrict__ Wq, const float* __restrict__ bq,
                           const float* __restrict__ Wk, const float* __restrict__ bk,
                           const float* __restrict__ Wv, const float* __restrict__ bv,
                           short* __restrict__ Qb, short* __restrict__ Kb,
                           short* __restrict__ Vt) {
    const int rb = blockIdx.x;
    const int cb = blockIdx.y;
    const int t  = threadIdx.x;
    const int r0 = rb * 8;
    const int gc = cb * 256 + t;     // 0..1535
    const int m  = gc >> 9;          // 0:Q 1:K 2:V
    const int cc = gc & 511;
    const float* W    = (m == 0) ? Wq : (m == 1) ? Wk : Wv;
    const float* bias = (m == 0) ? bq : (m == 1) ? bk : bv;
    const float4* xf4 = (const float4*)(x + (size_t)r0 * D);

    float acc[8];
#pragma unroll
    for (int r = 0; r < 8; ++r) acc[r] = 0.f;

    for (int k4 = 0; k4 < D / 4; ++k4) {
        float w0 = W[(k4 * 4 + 0) * 512 + cc];
        float w1 = W[(k4 * 4 + 1) * 512 + cc];
        float w2 = W[(k4 * 4 + 2) * 512 + cc];
        float w3 = W[(k4 * 4 + 3) * 512 + cc];
#pragma unroll
        for (int r = 0; r < 8; ++r) {
            float4 xv = xf4[r * (D / 4) + k4];   // uniform -> s_load broadcast
            acc[r] += xv.x * w0 + xv.y * w1 + xv.z * w2 + xv.w * w3;
        }
    }
    const float b = bias[cc];
    const int h = cc >> 6, d = cc & 63;
    const float scale = (m == 0) ? 0.125f : 1.0f;
#pragma unroll
    for (int r = 0; r < 8; ++r) {
        float val = (acc[r] + b) * scale;
        if (m == 0)      Qb[(((size_t)h * S + (r0 + r)) << 6) + d] = f2bf(val);
        else if (m == 1) Kb[(((size_t)h * S + (r0 + r)) << 6) + d] = f2bf(val);
        else             Vt[((size_t)h * 64 + d) * S + (r0 + r)]   = f2bf(val);
    }
}

// -------------------- K2: fused logits + entmax-1.5 + PV --------------------
// 512 threads = 8 waves per block; block owns 16 q-rows x full S. Wave w owns
// k-slice [w*384, w*384+384). Pass A: MFMA logits once, keep w=(logit)/2 in
// 48 packed-bf16 VGPRs; per-row max/sum/sumsq -> closed-form full-support
// init. Pass B: register-only Michelot iterations, cross-wave reduce via LDS.
// Final: P from registers -> fp32 attn (nontemporal) + LDS transpose -> PV
// MFMA partials -> cross-wave sum -> AO. h = bid&7 pins one head per XCD.
__global__ __launch_bounds__(512, 4) void fused_attn_kernel(
        const short* __restrict__ Qb, const short* __restrict__ Kb,
        const short* __restrict__ Vt, float* __restrict__ attn,
        float* __restrict__ AO) {
    __shared__ float sred[8][16][3];     // per-wave per-row stats
    __shared__ short plds[8][16][40];    // per-wave P transpose scratch
    __shared__ float pacc[8][16][64];    // per-wave PV partials
    const int bid = blockIdx.x;
    const int h = bid & 7, qt = bid >> 3;    // one head per XCD
    const int q0 = qt * 16;
    const int t = threadIdx.x;
    const int w = t >> 6, l = t & 63;
    const int lr = l & 15, lk = l >> 4;
    const int kbase = w * 384;

    const short* Qh = Qb + ((size_t)h * S) * 64;
    const short* Kh = Kb + ((size_t)h * S) * 64;
    const short* Vh = Vt + (size_t)h * 64 * S;

    const bf16x8 aq0 = *(const bf16x8*)(Qh + (size_t)(q0 + lr) * 64 + lk * 8);
    const bf16x8 aq1 = *(const bf16x8*)(Qh + (size_t)(q0 + lr) * 64 + 32 + lk * 8);

    // ---- Pass A: logits once; keep w-values packed bf16; per-row stats ----
    unsigned zw[12][4];
    float m4[4] = {-1e30f, -1e30f, -1e30f, -1e30f};
    float s4[4] = {}, q4[4] = {};
#pragma unroll
    for (int jp = 0; jp < 12; ++jp) {
        const short* kp = Kh + (size_t)(kbase + jp * 32 + lr) * 64;
        bf16x8 b00 = *(const bf16x8*)(kp + lk * 8);
        bf16x8 b01 = *(const bf16x8*)(kp + 32 + lk * 8);
        bf16x8 b10 = *(const bf16x8*)(kp + 16 * 64 + lk * 8);
        bf16x8 b11 = *(const bf16x8*)(kp + 16 * 64 + 32 + lk * 8);
        f32x4 d0 = (f32x4){0.f, 0.f, 0.f, 0.f}, d1 = d0;
        d0 = __builtin_amdgcn_mfma_f32_16x16x32_bf16(aq0, b00, d0, 0, 0, 0);
        d0 = __builtin_amdgcn_mfma_f32_16x16x32_bf16(aq1, b01, d0, 0, 0, 0);
        d1 = __builtin_amdgcn_mfma_f32_16x16x32_bf16(aq0, b10, d1, 0, 0, 0);
        d1 = __builtin_amdgcn_mfma_f32_16x16x32_bf16(aq1, b11, d1, 0, 0, 0);
#pragma unroll
        for (int r = 0; r < 4; ++r) {
            float w0 = d0[r] * 0.5f, w1 = d1[r] * 0.5f;
            m4[r] = fmaxf(m4[r], fmaxf(w0, w1));
            s4[r] += w0 + w1;
            q4[r] = fmaf(w0, w0, fmaf(w1, w1, q4[r]));
            zw[jp][r] = pack_rne(w0, w1);
        }
    }
#pragma unroll
    for (int off = 1; off < 16; off <<= 1) {
#pragma unroll
        for (int r = 0; r < 4; ++r) {
            m4[r] = fmaxf(m4[r], __shfl_xor(m4[r], off, 64));
            s4[r] += __shfl_xor(s4[r], off, 64);
            q4[r] += __shfl_xor(q4[r], off, 64);
        }
    }
    if (lr == 0) {
#pragma unroll
        for (int r = 0; r < 4; ++r) {
            sred[w][lk * 4 + r][0] = m4[r];
            sred[w][lk * 4 + r][1] = s4[r];
            sred[w][lk * 4 + r][2] = q4[r];
        }
    }
    __syncthreads();

    // ---- closed-form full-support init (w-space) ----
    const float n = (float)S;
    float Tj;
    {
        float mj = -1e30f, sj = 0.f, qj = 0.f;
#pragma unroll
        for (int ww = 0; ww < 8; ++ww) {
            mj = fmaxf(mj, sred[ww][lr][0]);
            sj += sred[ww][lr][1];
            qj += sred[ww][lr][2];
        }
        float mean = sj * (1.f / n);
        float msq  = qj * (1.f / n);
        float ssv  = n * (msq - mean * mean);
        Tj = mean - sqrtf(fmaxf((1.f - ssv) / n, 0.f));
        Tj = fminf(fmaxf(Tj, mj - 1.0f), mj - 0.01f);
    }
    float T4[4];
#pragma unroll
    for (int r = 0; r < 4; ++r) T4[r] = __shfl(Tj, lk * 4 + r, 64);
    __syncthreads();                       // sred reuse below

    // ---- Pass B: register-only Michelot iterations ----
    for (int it = 0; it < 8; ++it) {
        float f4[4] = {}, fp4[4] = {}, cn4[4] = {};
#pragma unroll
        for (int jp = 0; jp < 12; ++jp)
#pragma unroll
            for (int r = 0; r < 4; ++r) {
                unsigned pk = zw[jp][r];
                float z0 = unpk_lo(pk) - T4[r];
                float z1 = unpk_hi(pk) - T4[r];
                float zc0 = fmaxf(z0, 0.f), zc1 = fmaxf(z1, 0.f);
                f4[r]  = fmaf(zc0, zc0, fmaf(zc1, zc1, f4[r]));
                fp4[r] += zc0 + zc1;
                cn4[r] += (z0 > 0.f ? 1.f : 0.f) + (z1 > 0.f ? 1.f : 0.f);
            }
#pragma unroll
        for (int off = 1; off < 16; off <<= 1) {
#pragma unroll
            for (int r = 0; r < 4; ++r) {
                f4[r]  += __shfl_xor(f4[r],  off, 64);
                fp4[r] += __shfl_xor(fp4[r], off, 64);
                cn4[r] += __shfl_xor(cn4[r], off, 64);
            }
        }
        if (lr == 0) {
#pragma unroll
            for (int r = 0; r < 4; ++r) {
                sred[w][lk * 4 + r][0] = f4[r];
                sred[w][lk * 4 + r][1] = fp4[r];
                sred[w][lk * 4 + r][2] = cn4[r];
            }
        }
        __syncthreads();
        float fj = 0.f, fpj = 0.f, cnj = 0.f;
#pragma unroll
        for (int ww = 0; ww < 8; ++ww) {
            fj  += sred[ww][lr][0];
            fpj += sred[ww][lr][1];
            cnj += sred[ww][lr][2];
        }
        float ns   = fmaxf(cnj, 1.0f);
        float disc = fmaxf(fpj * fpj - ns * (fj - 1.0f), 0.f);
        float del  = (fpj - sqrtf(disc)) / ns;
#pragma unroll
        for (int r = 0; r < 4; ++r) T4[r] += __shfl(del, lk * 4 + r, 64);
        __syncthreads();                   // sred reuse next iter
        if (__all(fabsf(del) < 2e-6f)) break;   // uniform: same LDS sums everywhere
    }

    // ---- Final: P -> attn (nontemporal) + LDS transpose -> PV MFMA ----
    f32x4 acc[4];
#pragma unroll
    for (int j = 0; j < 4; ++j) acc[j] = (f32x4){0.f, 0.f, 0.f, 0.f};
    float* arow = attn + ((size_t)h * S + q0) * S;
#pragma unroll
    for (int jp = 0; jp < 12; ++jp) {
#pragma unroll
        for (int r = 0; r < 4; ++r) {
            unsigned pk = zw[jp][r];
            float zc0 = fmaxf(unpk_lo(pk) - T4[r], 0.f);
            float zc1 = fmaxf(unpk_hi(pk) - T4[r], 0.f);
            float p0 = zc0 * zc0, p1 = zc1 * zc1;
            const int row = lk * 4 + r;
            size_t cb = (size_t)row * S + kbase + jp * 32;
            __builtin_nontemporal_store(p0, &arow[cb + lr]);
            __builtin_nontemporal_store(p1, &arow[cb + 16 + lr]);
            plds[w][row][lr]      = f2bf(p0);
            plds[w][row][16 + lr] = f2bf(p1);
        }
        // same-wave LDS round-trip (compiler inserts lgkmcnt; no barrier)
        bf16x8 a = *(const bf16x8*)&plds[w][lr][lk * 8];
        const short* vp = Vh + kbase + jp * 32 + lk * 8;
#pragma unroll
        for (int j = 0; j < 4; ++j) {
            bf16x8 b = *(const bf16x8*)(vp + (size_t)(j * 16 + lr) * S);
            acc[j] = __builtin_amdgcn_mfma_f32_16x16x32_bf16(a, b, acc[j], 0, 0, 0);
        }
    }
    // cross-wave PV reduction
#pragma unroll
    for (int j = 0; j < 4; ++j)
#pragma unroll
        for (int r = 0; r < 4; ++r)
            pacc[w][lk * 4 + r][j * 16 + lr] = acc[j][r];
    __syncthreads();
    float* AOr = AO + ((size_t)h * S + q0) * 64;
#pragma unroll
    for (int u = 0; u < 2; ++u) {
        int idx = t + 512 * u;             // 0..1023
        int row = idx >> 6, col = idx & 63;
        float sum = 0.f;
#pragma unroll
        for (int ww = 0; ww < 8; ++ww) sum += pacc[ww][row][col];
        AOr[(size_t)row * 64 + col] = sum;
    }
}

// -------------------- K5: out-proj + residual + LayerNorm --------------------
__global__ void outproj_ln_kernel(const float* __restrict__ AO, const float* __restrict__ Wo,
                                  const float* __restrict__ bo, const float* __restrict__ x,
                                  const float* __restrict__ gamma, const float* __restrict__ beta,
                                  float* __restrict__ out) {
    __shared__ float red[8];
    const int rb = blockIdx.x;
    const int t  = threadIdx.x;
    const int s0 = rb * 8;
    float acc0[8] = {}, acc1[8] = {};
    const int c0 = t, c1 = t + 256;
    const float4* A0 = (const float4*)AO;
    for (int k4 = 0; k4 < 128; ++k4) {
        int k = k4 * 4;
        int h = k >> 6, d4 = (k & 63) >> 2;
        float w00 = Wo[(k + 0) * 512 + c0], w10 = Wo[(k + 0) * 512 + c1];
        float w01 = Wo[(k + 1) * 512 + c0], w11 = Wo[(k + 1) * 512 + c1];
        float w02 = Wo[(k + 2) * 512 + c0], w12 = Wo[(k + 2) * 512 + c1];
        float w03 = Wo[(k + 3) * 512 + c0], w13 = Wo[(k + 3) * 512 + c1];
#pragma unroll
        for (int r = 0; r < 8; ++r) {
            float4 a = A0[((size_t)h * S + s0 + r) * 16 + d4];   // uniform
            acc0[r] += a.x * w00 + a.y * w01 + a.z * w02 + a.w * w03;
            acc1[r] += a.x * w10 + a.y * w11 + a.z * w12 + a.w * w13;
        }
    }
    const float b0 = bo[c0], b1 = bo[c1];
    const float g0 = gamma[c0], g1 = gamma[c1];
    const float be0 = beta[c0], be1 = beta[c1];
    const int wave = t >> 6, lane = t & 63;
    for (int r = 0; r < 8; ++r) {
        float y0 = acc0[r] + b0 + x[(size_t)(s0 + r) * 512 + c0];
        float y1 = acc1[r] + b1 + x[(size_t)(s0 + r) * 512 + c1];
        float s = y0 + y1, qq = y0 * y0 + y1 * y1;
#pragma unroll
        for (int off = 32; off; off >>= 1) {
            s  += __shfl_down(s, off, 64);
            qq += __shfl_down(qq, off, 64);
        }
        __syncthreads();
        if (lane == 0) { red[wave * 2] = s; red[wave * 2 + 1] = qq; }
        __syncthreads();
        s  = red[0] + red[2] + red[4] + red[6];
        qq = red[1] + red[3] + red[5] + red[7];
        float mu  = s * (1.0f / 512.0f);
        float var = qq * (1.0f / 512.0f) - mu * mu;
        float inv = rsqrtf(var + LN_EPS);
        out[(size_t)(s0 + r) * 512 + c0] = (y0 - mu) * inv * g0 + be0;
        out[(size_t)(s0 + r) * 512 + c1] = (y1 - mu) * inv * g1 + be1;
    }
}

extern "C" void kernel_launch(void* const* d_in, const int* in_sizes, int n_in,
                              void* d_out, int out_size, void* d_ws, size_t ws_size,
                              hipStream_t stream) {
    const float* x     = (const float*)d_in[0];
    const float* Wq    = (const float*)d_in[1];
    const float* bq    = (const float*)d_in[2];
    const float* Wk    = (const float*)d_in[3];
    const float* bk    = (const float*)d_in[4];
    const float* Wv    = (const float*)d_in[5];
    const float* bv    = (const float*)d_in[6];
    const float* Wo    = (const float*)d_in[7];
    const float* bo    = (const float*)d_in[8];
    const float* gamma = (const float*)d_in[9];
    const float* beta  = (const float*)d_in[10];

    float* out  = (float*)d_out;
    float* attn = out + (size_t)S * D;          // tuple output #2

    short* Qb = (short*)d_ws;                   // [H][S][64] bf16, pre-scaled
    short* Kb = Qb + (size_t)H * S * 64;        // [H][S][64] bf16
    short* Vt = Kb + (size_t)H * S * 64;        // [H][64][S] bf16 (transposed)
    float* AO = (float*)(Vt + (size_t)H * 64 * S);   // [H][S][64] f32

    qkv_kernel<<<dim3(S / 8, 6), 256, 0, stream>>>(x, Wq, bq, Wk, bk, Wv, bv, Qb, Kb, Vt);
    fused_attn_kernel<<<dim3((S / 16) * H), 512, 0, stream>>>(Qb, Kb, Vt, attn, AO);
    outproj_ln_kernel<<<dim3(S / 8), 256, 0, stream>>>(AO, Wo, bo, x, gamma, beta, out);
}

// Round 7
// 414.490 us; speedup vs baseline: 1.7198x; 1.2931x over previous
//
#include <hip/hip_runtime.h>

#define S 3072
#define D 512
#define H 8

constexpr float LN_EPS = 1e-6f;

typedef __attribute__((ext_vector_type(8))) short bf16x8;   // 8 bf16 = 4 VGPRs
typedef __attribute__((ext_vector_type(4))) float f32x4;    // MFMA C/D frag

__device__ __forceinline__ short f2bf(float f) {            // RNE fp32->bf16
    unsigned int u = __builtin_bit_cast(unsigned int, f);
    u += 0x7FFFu + ((u >> 16) & 1u);
    return (short)(u >> 16);
}
__device__ __forceinline__ unsigned pack_rne(float lo, float hi) {   // 2xbf16 in u32
    unsigned ul = __builtin_bit_cast(unsigned, lo);
    ul += 0x7FFFu + ((ul >> 16) & 1u);
    unsigned uh = __builtin_bit_cast(unsigned, hi);
    uh += 0x7FFFu + ((uh >> 16) & 1u);
    return (ul >> 16) | (uh & 0xFFFF0000u);
}
__device__ __forceinline__ float unpk_lo(unsigned p) {
    return __builtin_bit_cast(float, p << 16);
}
__device__ __forceinline__ float unpk_hi(unsigned p) {
    return __builtin_bit_cast(float, p & 0xFFFF0000u);
}

// -------------------- K1: QKV projection --------------------
// x[S,D] @ {Wq,Wk,Wv}[D,512] + b -> bf16 Q,K in [H][S][64] (Q pre-scaled by
// 1/8) and bf16 V^T in [H][64][S]. grid (S/8, 6), block 256.
__global__ void qkv_kernel(const float* __restrict__ x,
                           const float* __restrict__ Wq, const float* __restrict__ bq,
                           const float* __restrict__ Wk, const float* __restrict__ bk,
                           const float* __restrict__ Wv, const float* __restrict__ bv,
                           short* __restrict__ Qb, short* __restrict__ Kb,
                           short* __restrict__ Vt) {
    const int rb = blockIdx.x;
    const int cb = blockIdx.y;
    const int t  = threadIdx.x;
    const int r0 = rb * 8;
    const int gc = cb * 256 + t;     // 0..1535
    const int m  = gc >> 9;          // 0:Q 1:K 2:V
    const int cc = gc & 511;
    const float* W    = (m == 0) ? Wq : (m == 1) ? Wk : Wv;
    const float* bias = (m == 0) ? bq : (m == 1) ? bk : bv;
    const float4* xf4 = (const float4*)(x + (size_t)r0 * D);

    float acc[8];
#pragma unroll
    for (int r = 0; r < 8; ++r) acc[r] = 0.f;

    for (int k4 = 0; k4 < D / 4; ++k4) {
        float w0 = W[(k4 * 4 + 0) * 512 + cc];
        float w1 = W[(k4 * 4 + 1) * 512 + cc];
        float w2 = W[(k4 * 4 + 2) * 512 + cc];
        float w3 = W[(k4 * 4 + 3) * 512 + cc];
#pragma unroll
        for (int r = 0; r < 8; ++r) {
            float4 xv = xf4[r * (D / 4) + k4];   // uniform -> s_load broadcast
            acc[r] += xv.x * w0 + xv.y * w1 + xv.z * w2 + xv.w * w3;
        }
    }
    const float b = bias[cc];
    const int h = cc >> 6, d = cc & 63;
    const float scale = (m == 0) ? 0.125f : 1.0f;
#pragma unroll
    for (int r = 0; r < 8; ++r) {
        float val = (acc[r] + b) * scale;
        if (m == 0)      Qb[(((size_t)h * S + (r0 + r)) << 6) + d] = f2bf(val);
        else if (m == 1) Kb[(((size_t)h * S + (r0 + r)) << 6) + d] = f2bf(val);
        else             Vt[((size_t)h * 64 + d) * S + (r0 + r)]   = f2bf(val);
    }
}

// -------------------- K2: fused logits + entmax-1.5 + PV --------------------
// 512 threads = 8 waves per block; block owns 16 q-rows x full S. Wave w owns
// k-slice [w*384, w*384+384). Pass A: MFMA logits once, keep w=(logit)/2 in
// 48 packed-bf16 VGPRs; per-row max/sum/sumsq -> closed-form full-support
// init. Pass B: register-only Michelot iterations, cross-wave reduce via LDS.
// Final: P from registers -> fp32 attn (nontemporal) + LDS transpose -> PV
// MFMA partials -> cross-wave sum -> AO. h = bid&7 pins one head per XCD.
// launch_bounds(512, 2): 2 blocks/CU -> 128-VGPR cap. Round-6's (512,4)
// empirically capped VGPR at 64 and spilled zw (FETCH +470 MB of scratch).
__global__ __launch_bounds__(512, 2) void fused_attn_kernel(
        const short* __restrict__ Qb, const short* __restrict__ Kb,
        const short* __restrict__ Vt, float* __restrict__ attn,
        float* __restrict__ AO) {
    __shared__ float sred[8][16][3];     // per-wave per-row stats
    __shared__ short plds[8][16][40];    // per-wave P transpose scratch
    __shared__ float pacc[8][16][64];    // per-wave PV partials
    const int bid = blockIdx.x;
    const int h = bid & 7, qt = bid >> 3;    // one head per XCD
    const int q0 = qt * 16;
    const int t = threadIdx.x;
    const int w = t >> 6, l = t & 63;
    const int lr = l & 15, lk = l >> 4;
    const int kbase = w * 384;

    const short* Qh = Qb + ((size_t)h * S) * 64;
    const short* Kh = Kb + ((size_t)h * S) * 64;
    const short* Vh = Vt + (size_t)h * 64 * S;

    const bf16x8 aq0 = *(const bf16x8*)(Qh + (size_t)(q0 + lr) * 64 + lk * 8);
    const bf16x8 aq1 = *(const bf16x8*)(Qh + (size_t)(q0 + lr) * 64 + 32 + lk * 8);

    // ---- Pass A: logits once; keep w-values packed bf16; per-row stats ----
    unsigned zw[12][4];
    float m4[4] = {-1e30f, -1e30f, -1e30f, -1e30f};
    float s4[4] = {}, q4[4] = {};
#pragma unroll
    for (int jp = 0; jp < 12; ++jp) {
        const short* kp = Kh + (size_t)(kbase + jp * 32 + lr) * 64;
        bf16x8 b00 = *(const bf16x8*)(kp + lk * 8);
        bf16x8 b01 = *(const bf16x8*)(kp + 32 + lk * 8);
        bf16x8 b10 = *(const bf16x8*)(kp + 16 * 64 + lk * 8);
        bf16x8 b11 = *(const bf16x8*)(kp + 16 * 64 + 32 + lk * 8);
        f32x4 d0 = (f32x4){0.f, 0.f, 0.f, 0.f}, d1 = d0;
        d0 = __builtin_amdgcn_mfma_f32_16x16x32_bf16(aq0, b00, d0, 0, 0, 0);
        d0 = __builtin_amdgcn_mfma_f32_16x16x32_bf16(aq1, b01, d0, 0, 0, 0);
        d1 = __builtin_amdgcn_mfma_f32_16x16x32_bf16(aq0, b10, d1, 0, 0, 0);
        d1 = __builtin_amdgcn_mfma_f32_16x16x32_bf16(aq1, b11, d1, 0, 0, 0);
#pragma unroll
        for (int r = 0; r < 4; ++r) {
            float w0 = d0[r] * 0.5f, w1 = d1[r] * 0.5f;
            m4[r] = fmaxf(m4[r], fmaxf(w0, w1));
            s4[r] += w0 + w1;
            q4[r] = fmaf(w0, w0, fmaf(w1, w1, q4[r]));
            zw[jp][r] = pack_rne(w0, w1);
        }
    }
#pragma unroll
    for (int off = 1; off < 16; off <<= 1) {
#pragma unroll
        for (int r = 0; r < 4; ++r) {
            m4[r] = fmaxf(m4[r], __shfl_xor(m4[r], off, 64));
            s4[r] += __shfl_xor(s4[r], off, 64);
            q4[r] += __shfl_xor(q4[r], off, 64);
        }
    }
    if (lr == 0) {
#pragma unroll
        for (int r = 0; r < 4; ++r) {
            sred[w][lk * 4 + r][0] = m4[r];
            sred[w][lk * 4 + r][1] = s4[r];
            sred[w][lk * 4 + r][2] = q4[r];
        }
    }
    __syncthreads();

    // ---- closed-form full-support init (w-space) ----
    const float n = (float)S;
    float Tj;
    {
        float mj = -1e30f, sj = 0.f, qj = 0.f;
#pragma unroll
        for (int ww = 0; ww < 8; ++ww) {
            mj = fmaxf(mj, sred[ww][lr][0]);
            sj += sred[ww][lr][1];
            qj += sred[ww][lr][2];
        }
        float mean = sj * (1.f / n);
        float msq  = qj * (1.f / n);
        float ssv  = n * (msq - mean * mean);
        Tj = mean - sqrtf(fmaxf((1.f - ssv) / n, 0.f));
        Tj = fminf(fmaxf(Tj, mj - 1.0f), mj - 0.01f);
    }
    float T4[4];
#pragma unroll
    for (int r = 0; r < 4; ++r) T4[r] = __shfl(Tj, lk * 4 + r, 64);
    __syncthreads();                       // sred reuse below

    // ---- Pass B: register-only Michelot iterations ----
    for (int it = 0; it < 8; ++it) {
        float f4[4] = {}, fp4[4] = {}, cn4[4] = {};
#pragma unroll
        for (int jp = 0; jp < 12; ++jp)
#pragma unroll
            for (int r = 0; r < 4; ++r) {
                unsigned pk = zw[jp][r];
                float z0 = unpk_lo(pk) - T4[r];
                float z1 = unpk_hi(pk) - T4[r];
                float zc0 = fmaxf(z0, 0.f), zc1 = fmaxf(z1, 0.f);
                f4[r]  = fmaf(zc0, zc0, fmaf(zc1, zc1, f4[r]));
                fp4[r] += zc0 + zc1;
                cn4[r] += (z0 > 0.f ? 1.f : 0.f) + (z1 > 0.f ? 1.f : 0.f);
            }
#pragma unroll
        for (int off = 1; off < 16; off <<= 1) {
#pragma unroll
            for (int r = 0; r < 4; ++r) {
                f4[r]  += __shfl_xor(f4[r],  off, 64);
                fp4[r] += __shfl_xor(fp4[r], off, 64);
                cn4[r] += __shfl_xor(cn4[r], off, 64);
            }
        }
        if (lr == 0) {
#pragma unroll
            for (int r = 0; r < 4; ++r) {
                sred[w][lk * 4 + r][0] = f4[r];
                sred[w][lk * 4 + r][1] = fp4[r];
                sred[w][lk * 4 + r][2] = cn4[r];
            }
        }
        __syncthreads();
        float fj = 0.f, fpj = 0.f, cnj = 0.f;
#pragma unroll
        for (int ww = 0; ww < 8; ++ww) {
            fj  += sred[ww][lr][0];
            fpj += sred[ww][lr][1];
            cnj += sred[ww][lr][2];
        }
        float ns   = fmaxf(cnj, 1.0f);
        float disc = fmaxf(fpj * fpj - ns * (fj - 1.0f), 0.f);
        float del  = (fpj - sqrtf(disc)) / ns;
#pragma unroll
        for (int r = 0; r < 4; ++r) T4[r] += __shfl(del, lk * 4 + r, 64);
        __syncthreads();                   // sred reuse next iter
        if (__all(fabsf(del) < 2e-6f)) break;   // uniform: same LDS sums everywhere
    }

    // ---- Final: P -> attn (nontemporal) + LDS transpose -> PV MFMA ----
    f32x4 acc[4];
#pragma unroll
    for (int j = 0; j < 4; ++j) acc[j] = (f32x4){0.f, 0.f, 0.f, 0.f};
    float* arow = attn + ((size_t)h * S + q0) * S;
#pragma unroll
    for (int jp = 0; jp < 12; ++jp) {
#pragma unroll
        for (int r = 0; r < 4; ++r) {
            unsigned pk = zw[jp][r];
            float zc0 = fmaxf(unpk_lo(pk) - T4[r], 0.f);
            float zc1 = fmaxf(unpk_hi(pk) - T4[r], 0.f);
            float p0 = zc0 * zc0, p1 = zc1 * zc1;
            const int row = lk * 4 + r;
            size_t cb = (size_t)row * S + kbase + jp * 32;
            __builtin_nontemporal_store(p0, &arow[cb + lr]);
            __builtin_nontemporal_store(p1, &arow[cb + 16 + lr]);
            plds[w][row][lr]      = f2bf(p0);
            plds[w][row][16 + lr] = f2bf(p1);
        }
        // same-wave LDS round-trip (compiler inserts lgkmcnt; no barrier)
        bf16x8 a = *(const bf16x8*)&plds[w][lr][lk * 8];
        const short* vp = Vh + kbase + jp * 32 + lk * 8;
#pragma unroll
        for (int j = 0; j < 4; ++j) {
            bf16x8 b = *(const bf16x8*)(vp + (size_t)(j * 16 + lr) * S);
            acc[j] = __builtin_amdgcn_mfma_f32_16x16x32_bf16(a, b, acc[j], 0, 0, 0);
        }
    }
    // cross-wave PV reduction
#pragma unroll
    for (int j = 0; j < 4; ++j)
#pragma unroll
        for (int r = 0; r < 4; ++r)
            pacc[w][lk * 4 + r][j * 16 + lr] = acc[j][r];
    __syncthreads();
    float* AOr = AO + ((size_t)h * S + q0) * 64;
#pragma unroll
    for (int u = 0; u < 2; ++u) {
        int idx = t + 512 * u;             // 0..1023
        int row = idx >> 6, col = idx & 63;
        float sum = 0.f;
#pragma unroll
        for (int ww = 0; ww < 8; ++ww) sum += pacc[ww][row][col];
        AOr[(size_t)row * 64 + col] = sum;
    }
}

// -------------------- K5: out-proj + residual + LayerNorm --------------------
__global__ void outproj_ln_kernel(const float* __restrict__ AO, const float* __restrict__ Wo,
                                  const float* __restrict__ bo, const float* __restrict__ x,
                                  const float* __restrict__ gamma, const float* __restrict__ beta,
                                  float* __restrict__ out) {
    __shared__ float red[8];
    const int rb = blockIdx.x;
    const int t  = threadIdx.x;
    const int s0 = rb * 8;
    float acc0[8] = {}, acc1[8] = {};
    const int c0 = t, c1 = t + 256;
    const float4* A0 = (const float4*)AO;
    for (int k4 = 0; k4 < 128; ++k4) {
        int k = k4 * 4;
        int h = k >> 6, d4 = (k & 63) >> 2;
        float w00 = Wo[(k + 0) * 512 + c0], w10 = Wo[(k + 0) * 512 + c1];
        float w01 = Wo[(k + 1) * 512 + c0], w11 = Wo[(k + 1) * 512 + c1];
        float w02 = Wo[(k + 2) * 512 + c0], w12 = Wo[(k + 2) * 512 + c1];
        float w03 = Wo[(k + 3) * 512 + c0], w13 = Wo[(k + 3) * 512 + c1];
#pragma unroll
        for (int r = 0; r < 8; ++r) {
            float4 a = A0[((size_t)h * S + s0 + r) * 16 + d4];   // uniform
            acc0[r] += a.x * w00 + a.y * w01 + a.z * w02 + a.w * w03;
            acc1[r] += a.x * w10 + a.y * w11 + a.z * w12 + a.w * w13;
        }
    }
    const float b0 = bo[c0], b1 = bo[c1];
    const float g0 = gamma[c0], g1 = gamma[c1];
    const float be0 = beta[c0], be1 = beta[c1];
    const int wave = t >> 6, lane = t & 63;
    for (int r = 0; r < 8; ++r) {
        float y0 = acc0[r] + b0 + x[(size_t)(s0 + r) * 512 + c0];
        float y1 = acc1[r] + b1 + x[(size_t)(s0 + r) * 512 + c1];
        float s = y0 + y1, qq = y0 * y0 + y1 * y1;
#pragma unroll
        for (int off = 32; off; off >>= 1) {
            s  += __shfl_down(s, off, 64);
            qq += __shfl_down(qq, off, 64);
        }
        __syncthreads();
        if (lane == 0) { red[wave * 2] = s; red[wave * 2 + 1] = qq; }
        __syncthreads();
        s  = red[0] + red[2] + red[4] + red[6];
        qq = red[1] + red[3] + red[5] + red[7];
        float mu  = s * (1.0f / 512.0f);
        float var = qq * (1.0f / 512.0f) - mu * mu;
        float inv = rsqrtf(var + LN_EPS);
        out[(size_t)(s0 + r) * 512 + c0] = (y0 - mu) * inv * g0 + be0;
        out[(size_t)(s0 + r) * 512 + c1] = (y1 - mu) * inv * g1 + be1;
    }
}

extern "C" void kernel_launch(void* const* d_in, const int* in_sizes, int n_in,
                              void* d_out, int out_size, void* d_ws, size_t ws_size,
                              hipStream_t stream) {
    const float* x     = (const float*)d_in[0];
    const float* Wq    = (const float*)d_in[1];
    const float* bq    = (const float*)d_in[2];
    const float* Wk    = (const float*)d_in[3];
    const float* bk    = (const float*)d_in[4];
    const float* Wv    = (const float*)d_in[5];
    const float* bv    = (const float*)d_in[6];
    const float* Wo    = (const float*)d_in[7];
    const float* bo    = (const float*)d_in[8];
    const float* gamma = (const float*)d_in[9];
    const float* beta  = (const float*)d_in[10];

    float* out  = (float*)d_out;
    float* attn = out + (size_t)S * D;          // tuple output #2

    short* Qb = (short*)d_ws;                   // [H][S][64] bf16, pre-scaled
    short* Kb = Qb + (size_t)H * S * 64;        // [H][S][64] bf16
    short* Vt = Kb + (size_t)H * S * 64;        // [H][64][S] bf16 (transposed)
    float* AO = (float*)(Vt + (size_t)H * 64 * S);   // [H][S][64] f32

    qkv_kernel<<<dim3(S / 8, 6), 256, 0, stream>>>(x, Wq, bq, Wk, bk, Wv, bv, Qb, Kb, Vt);
    fused_attn_kernel<<<dim3((S / 16) * H), 512, 0, stream>>>(Qb, Kb, Vt, attn, AO);
    outproj_ln_kernel<<<dim3(S / 8), 256, 0, stream>>>(AO, Wo, bo, x, gamma, beta, out);
}